// Round 11
// baseline (46.598 us; speedup 1.0000x reference)
//
#include <hip/hip_runtime.h>

#define L_SEQ 2048
#define HEADS 16
#define DIM   64
#define TILE  32
#define NTILES 4          // tiles per persistent block
#define XROWS 34          // x rows staged: l0-1 .. l0+32
#define XPITCH 68         // f32 pitch (272B)
#define DROWS 48          // delta rows padded to 3 tiles of 16

typedef __attribute__((ext_vector_type(8))) short bf16x8;
typedef __attribute__((ext_vector_type(4))) float f32x4;

// bf16(W^T W), recomputed from W on every launch (graph-capture safe)
__device__ unsigned short g_mbf[DIM * DIM];

static __device__ __forceinline__ unsigned short f2bf_rtne(float f) {
    unsigned int u = __builtin_bit_cast(unsigned int, f);
    u += 0x7fffu + ((u >> 16) & 1u);
    return (unsigned short)(u >> 16);
}
// pack hi16(a) | hi16(b)<<16 in ONE v_perm_b32 (truncation — score-path error
// budget is ~1000x the threshold sensitivity)
static __device__ __forceinline__ unsigned int pk2(float a, float b) {
    return __builtin_amdgcn_perm(__builtin_bit_cast(unsigned int, b),
                                 __builtin_bit_cast(unsigned int, a), 0x07060302u);
}
static __device__ __forceinline__ float bfhi(unsigned int u) {   // low16 -> f32
    return __builtin_bit_cast(float, u << 16);
}
static __device__ __forceinline__ float bflo(unsigned int u) {   // high16 -> f32
    return __builtin_bit_cast(float, u & 0xffff0000u);
}

// bf16 LDS tiles: XOR-swizzle ushort_col ^ ((row&7)<<3) == byte ^ ((row&7)<<4)
#define SWZ(row, col) ((row) * 64 + ((col) ^ (((row) & 7) * 8)))

// M[i][j] = sum_e W[e][i]*W[e][j]
__global__ void prep_m_kernel(const float* __restrict__ W) {
    const int i = blockIdx.x, j = threadIdx.x;
    float acc = 0.f;
    #pragma unroll 8
    for (int e = 0; e < DIM; ++e)
        acc = fmaf(W[e * DIM + i], W[e * DIM + j], acc);
    g_mbf[i * DIM + j] = f2bf_rtne(acc);
}

// R11 = R10's validated math inside a PERSISTENT-BLOCK pipeline:
// 2048 blocks (8/CU pinned residency), 4 tiles each, register prefetch of
// tile t+2's x rows issued during tile t's score phase (T14 issue-early /
// write-late), 3 barriers per tile.
__global__ __launch_bounds__(256, 8) void betweenness_rope_kernel(
    const float* __restrict__ x, const float* __restrict__ gate,
    float* __restrict__ out)
{
    __shared__ float xs[XROWS * XPITCH];          // staged x rows (f32)
    __shared__ unsigned short dl[DROWS * 64];     // bf16 delta rows, swizzled
    __shared__ float psq[4][DROWS];               // per-wave partial ||W d_r||^2
    __shared__ float ppr[4][DROWS];               // per-wave partial (W d_r).(W d_{r+1})
    __shared__ float2 fl[TILE];                   // per-row {floor(adj_pos), frac}

    const int tid  = threadIdx.x;
    const int lane = tid & 63;
    const int wv   = tid >> 6;
    const int la   = lane & 15, lg = lane >> 4;
    const int h    = blockIdx.y;
    const int b    = blockIdx.z;
    const int bh_off = (b * L_SEQ * HEADS + h) * DIM;
    const int l0q  = blockIdx.x * (TILE * NTILES);   // 128-row span per block
    const float gate0 = gate[0];

    // staging item map: item tid -> (row tid>>3, col (tid&7)*8); threads 0..15
    // carry a second item for rows 32..33
    const int r_a = tid >> 3, c_a = (tid & 7) * 8;
    const bool hasB = (tid < 16);
    const int r_b = 32 + (tid >> 3);              // 32 or 33 (tid<16 only)

    float4 pfa0, pfa1, pfb0 = {0,0,0,0}, pfb1 = {0,0,0,0};
    auto prefetch = [&](int tt) {                 // issue global loads -> regs
        int l0t = l0q + tt * TILE;
        int ga = max(0, min(L_SEQ - 1, l0t - 1 + r_a));
        const float* pa = x + bh_off + ga * (HEADS * DIM) + c_a;
        pfa0 = *(const float4*)pa;
        pfa1 = *(const float4*)(pa + 4);
        if (hasB) {
            int gb = max(0, min(L_SEQ - 1, l0t - 1 + r_b));
            const float* pb = x + bh_off + gb * (HEADS * DIM) + c_a;
            pfb0 = *(const float4*)pb;
            pfb1 = *(const float4*)(pb + 4);
        }
    };
    auto write_xs = [&]() {                       // regs -> LDS (waits vmcnt)
        *(float4*)&xs[r_a * XPITCH + c_a]     = pfa0;
        *(float4*)&xs[r_a * XPITCH + c_a + 4] = pfa1;
        if (hasB) {
            *(float4*)&xs[r_b * XPITCH + c_a]     = pfb0;
            *(float4*)&xs[r_b * XPITCH + c_a + 4] = pfb1;
        }
    };

    // epilogue constants (hoisted)
    const int j = lane & 31, half = lane >> 5;
    const int r0w = wv * 2 + half;                // base row 0..7
    const float fjr = __builtin_exp2f(-0.4152410118609203f * (float)j)
                    * 0.15915494309189535f;       // f_j/(2pi)
    const float cf = __builtin_amdgcn_cosf(fjr);
    const float sf = __builtin_amdgcn_sinf(fjr);
    const float cfm1 = cf - 1.0f;

    // one-time: zero dl rows 33..47 (never touched again)
    if (tid < 120) {
        int r = 33 + (tid >> 3), c0 = (tid & 7) * 8;
        uint4 z = {0u, 0u, 0u, 0u};
        *(uint4*)&dl[SWZ(r, c0)] = z;
    }

    prefetch(0);
    write_xs();
    prefetch(1);
    __syncthreads();                              // xs(0) + zero-fill visible

    for (int it = 0; it < NTILES; ++it) {
        const int l0 = l0q + it * TILE;

        // ---- [A] delta rows from xs; epilogue x values -> regs ----
        {
            float4 a0 = *(float4*)&xs[r_a * XPITCH + c_a];
            float4 a1 = *(float4*)&xs[r_a * XPITCH + c_a + 4];
            float4 b0 = *(float4*)&xs[(r_a + 1) * XPITCH + c_a];
            float4 b1 = *(float4*)&xs[(r_a + 1) * XPITCH + c_a + 4];
            uint4 o;
            o.x = pk2(b0.x - a0.x, b0.y - a0.y);
            o.y = pk2(b0.z - a0.z, b0.w - a0.w);
            o.z = pk2(b1.x - a1.x, b1.y - a1.y);
            o.w = pk2(b1.z - a1.z, b1.w - a1.w);
            *(uint4*)&dl[SWZ(r_a, c_a)] = o;
            if (tid < 8) {                        // delta row 32
                float4 c0v = *(float4*)&xs[32 * XPITCH + c_a];
                float4 c1v = *(float4*)&xs[32 * XPITCH + c_a + 4];
                float4 d0v = *(float4*)&xs[33 * XPITCH + c_a];
                float4 d1v = *(float4*)&xs[33 * XPITCH + c_a + 4];
                uint4 o2;
                o2.x = pk2(d0v.x - c0v.x, d0v.y - c0v.y);
                o2.y = pk2(d0v.z - c0v.z, d0v.w - c0v.w);
                o2.z = pk2(d1v.x - c1v.x, d1v.y - c1v.y);
                o2.w = pk2(d1v.z - c1v.z, d1v.w - c1v.w);
                *(uint4*)&dl[SWZ(32, c_a)] = o2;
            }
        }
        float2 xv[4];
        #pragma unroll
        for (int k = 0; k < 4; ++k)
            xv[k] = *(const float2*)&xs[(r0w + 1 + 8 * k) * XPITCH + 2 * j];
        __syncthreads();   // bar_a: dl ready, xs free

        // ---- [B] F^T = M @ Delta^T + band dots (R10-validated) ----
        {
            const int abase = (16 * wv + la) * 64 + lg * 8;
            bf16x8 ma0 = *(const bf16x8*)&g_mbf[abase];
            bf16x8 ma1 = *(const bf16x8*)&g_mbf[abase + 32];
            const int c = 16 * wv + 4 * lg;       // this lane's 4 e-columns
            #pragma unroll
            for (int rt = 0; rt < 3; ++rt) {
                int br = 16 * rt + la;
                bf16x8 bb0 = *(const bf16x8*)&dl[SWZ(br, lg * 8)];
                bf16x8 bb1 = *(const bf16x8*)&dl[SWZ(br, lg * 8 + 32)];
                f32x4 d = {0.f, 0.f, 0.f, 0.f};
                d = __builtin_amdgcn_mfma_f32_16x16x32_bf16(ma0, bb0, d, 0, 0, 0);
                d = __builtin_amdgcn_mfma_f32_16x16x32_bf16(ma1, bb1, d, 0, 0, 0);
                uint2 duv = *(const uint2*)&dl[SWZ(br, c)];
                int br1 = min(br + 1, DROWS - 1);
                uint2 dvv = *(const uint2*)&dl[SWZ(br1, c)];
                float n1p = d[0] * bfhi(duv.x);
                n1p = fmaf(d[1], bflo(duv.x), n1p);
                n1p = fmaf(d[2], bfhi(duv.y), n1p);
                n1p = fmaf(d[3], bflo(duv.y), n1p);
                float g1p = d[0] * bfhi(dvv.x);
                g1p = fmaf(d[1], bflo(dvv.x), g1p);
                g1p = fmaf(d[2], bfhi(dvv.y), g1p);
                g1p = fmaf(d[3], bflo(dvv.y), g1p);
                n1p += __shfl_xor(n1p, 16, 64);
                g1p += __shfl_xor(g1p, 16, 64);
                n1p += __shfl_xor(n1p, 32, 64);
                g1p += __shfl_xor(g1p, 32, 64);
                if (lg == 0) { psq[wv][br] = n1p; ppr[wv][br] = g1p; }
            }
        }
        if (it + 1 < NTILES) write_xs();          // stage next tile (vmcnt wait)
        __syncthreads();   // bar_b: psq/ppr ready, xs(it+1) ready

        // ---- [C] per-row score (32 threads); issue prefetch(it+2) ----
        if (tid < TILE) {
            int r = tid, l = l0 + r;
            float n1a = psq[0][r]     + psq[1][r]     + psq[2][r]     + psq[3][r];
            float n1b = psq[0][r + 1] + psq[1][r + 1] + psq[2][r + 1] + psq[3][r + 1];
            float gg  = ppr[0][r]     + ppr[1][r]     + ppr[2][r]     + ppr[3][r];
            float d1a = sqrtf(n1a), d1b = sqrtf(n1b);
            float dd  = sqrtf(fmaxf(n1a + n1b + 2.f * gg, 0.f));
            float sc  = fmaxf(1.f - ((d1a + d1b) - dd) / fmaxf(dd, 1e-6f), 0.f);
            float bet = (l >= 1 && l <= L_SEQ - 2) ? sc * (1.f / (L_SEQ - 2)) : 0.f;
            float adjust = gate0 * (bet - 0.5f) * 0.1f;
            float ap  = fminf(fmaxf((float)l + adjust, 0.f), (float)(L_SEQ - 1));
            float flo = floorf(ap);
            fl[r] = make_float2(flo, ap - flo);
        }
        if (it < NTILES - 2) prefetch(it + 2);    // in flight across 2+ phases
        __syncthreads();   // bar_c: fl ready

        // ---- [D] RoPE epilogue — registers only ----
        {
            float* obase = out + bh_off + (l0 + r0w) * (HEADS * DIM) + 2 * j;
            #pragma unroll
            for (int k = 0; k < 4; ++k) {
                int r = k * 8 + r0w;
                float2 ff = fl[r];
                float t0 = ff.x * fjr;
                float rv = t0 - floorf(t0);
                float c_lo = __builtin_amdgcn_cosf(rv);
                float s_lo = __builtin_amdgcn_sinf(rv);
                float u = fmaf(ff.y, cfm1, 1.0f);
                float v = ff.y * sf;
                float ci = fmaf(-s_lo, v, c_lo * u);
                float si = fmaf(c_lo, v, s_lo * u);
                float2 o;
                o.x = xv[k].x * ci - xv[k].y * si;
                o.y = fmaf(xv[k].y, ci, xv[k].x * si);
                *(float2*)(obase + k * 8 * (HEADS * DIM)) = o;
            }
        }
        // no barrier here: next [A] writes dl (readers were [B], behind bar_b)
        // and reads xs(it+1) (written in [B], behind bar_b)
    }
}

extern "C" void kernel_launch(void* const* d_in, const int* in_sizes, int n_in,
                              void* d_out, int out_size, void* d_ws, size_t ws_size,
                              hipStream_t stream) {
    const float* x    = (const float*)d_in[0];
    const float* W    = (const float*)d_in[1];
    const float* gate = (const float*)d_in[3];   // bias cancels in differences
    float* out = (float*)d_out;

    const int B = in_sizes[0] / (L_SEQ * HEADS * DIM);

    prep_m_kernel<<<DIM, DIM, 0, stream>>>(W);   // M = W^T W

    // 16 quarters x 16 heads x B batches = 2048 persistent blocks (8/CU)
    dim3 grid(L_SEQ / (TILE * NTILES), HEADS, B);
    betweenness_rope_kernel<<<grid, 256, 0, stream>>>(x, gate, out);
}